// Round 5
// baseline (242.122 us; speedup 1.0000x reference)
//
#include <hip/hip_runtime.h>
#include <hip/hip_bf16.h>
#include <stdint.h>

// SimpleSSM: y = (scan_t h=tanh(A*h + x@W_B^T + b_B)) @ W_C^T + b_C
// B=8, L=2048, D=1024.  All fp32 in/out.
// R5: GEMM1 fuses the x fp32->fp16(hi,lo) split into A-staging (reg-staged,
// T14 early-issue; B weights stay global_load_lds). Split is mandatory
// (R2/R3: plain bf16 AND fp16 both chaos-amplify to 0.25 absmax; R1/R4
// splits pass at 0.0156). Recurrence: 4-dep-op chain on r-state
// (h = 1-2r), c_t = a2+bx precomputed, output off-chain. Weights convert
// fused to one kernel. XCD-bijective tile remap everywhere.

using half8 = __attribute__((ext_vector_type(8))) _Float16;  // 8 fp16
using f32x4 = __attribute__((ext_vector_type(4))) float;

#define DEV __device__ __forceinline__

#if __has_builtin(__builtin_amdgcn_exp2f)
DEV float pexp(float x) { return __builtin_amdgcn_exp2f(x); }
constexpr float BX_SCALE = 2.8853900817779268f;   // 2*log2(e): exp2 domain
#else
DEV float pexp(float x) { return __expf(x); }
constexpr float BX_SCALE = 2.0f;                   // e^x domain
#endif

DEV ushort f2h(float x) {
  union { _Float16 f; ushort u; } c;
  c.f = (_Float16)x;          // v_cvt_f16_f32, RNE
  return c.u;
}
DEV float h2f(ushort u) {
  union { ushort u; _Float16 f; } c;
  c.u = u;
  return (float)c.f;
}

DEV void gload_lds16(const void* g, void* l) {
  __builtin_amdgcn_global_load_lds((const __attribute__((address_space(1))) void*)g,
                                   (__attribute__((address_space(3))) void*)l,
                                   16, 0, 0);
}

// ---------------- fused weights conversion ----------------
// W_B -> fp16 hi+lo split; W_C -> fp16.  One launch.
__global__ void k_convert_weights(const float* __restrict__ WB, const float* __restrict__ WC,
                                  ushort* __restrict__ wbh, ushort* __restrict__ wbl,
                                  ushort* __restrict__ wch, int n4) {
  const int stride = gridDim.x * blockDim.x;
  for (int i = blockIdx.x * blockDim.x + threadIdx.x; i < 2 * n4; i += stride) {
    if (i < n4) {
      float4 v = reinterpret_cast<const float4*>(WB)[i];
      ushort4 hv, lv;
      hv.x = f2h(v.x); lv.x = f2h(v.x - h2f(hv.x));
      hv.y = f2h(v.y); lv.y = f2h(v.y - h2f(hv.y));
      hv.z = f2h(v.z); lv.z = f2h(v.z - h2f(hv.z));
      hv.w = f2h(v.w); lv.w = f2h(v.w - h2f(hv.w));
      reinterpret_cast<ushort4*>(wbh)[i] = hv;
      reinterpret_cast<ushort4*>(wbl)[i] = lv;
    } else {
      const int j = i - n4;
      float4 v = reinterpret_cast<const float4*>(WC)[j];
      ushort4 hv;
      hv.x = f2h(v.x); hv.y = f2h(v.y);
      hv.z = f2h(v.z); hv.w = f2h(v.w);
      reinterpret_cast<ushort4*>(wch)[j] = hv;
    }
  }
}

// ---------------- GEMM1: Bx = BX_SCALE*(x @ W_B^T + b_B), split-fp16 -------
// A = x fp32 [M,K], split to (hi,lo) on the fly; B = weights hi/lo fp16.
// 128x128 tile, BK=64, 4 waves (2x2). acc += Ah*Bh + Al*Bh + Ah*Bl.
// A: reg-staged (8x float4/thread issued BEFORE the MFMA phase — latency
// hides under compute), split in regs, ds_write to SWIZZLED offsets.
// B: global_load_lds with pre-swizzled source (rule #21).
__global__ __launch_bounds__(256, 2)
void k_gemm1_fused(const float* __restrict__ X, const ushort* __restrict__ Bh,
                   const ushort* __restrict__ Bl, const float* __restrict__ bias,
                   float* __restrict__ C, int M, int N, int K) {
  __shared__ __align__(1024) ushort lds[4 * 128 * 64];
  ushort* sAh = lds;
  ushort* sAl = lds + 8192;
  ushort* sBh = lds + 16384;
  ushort* sBl = lds + 24576;

  const int t = threadIdx.x;
  const int lane = t & 63;
  const int w = t >> 6;
  const int wm = w >> 1, wn = w & 1;

  // XCD-bijective remap (grid 8 x 128): l=8*by+bx, xcd=l&7, s=l>>3;
  // bm=(s&~7)|xcd, bn=s&7.
  int bm, bn;
  {
    const int l = blockIdx.y * 8 + blockIdx.x;
    const int xcd = l & 7, s = l >> 3;
    bm = ((s >> 3) << 3) | xcd;
    bn = s & 7;
  }

  const int lr = lane & 15;
  const int lk = (lane >> 4) << 3;

  const float*  gA  = X  + (size_t)(bm * 128) * K;
  const ushort* gBh = Bh + (size_t)(bn * 128) * K;
  const ushort* gBl = Bl + (size_t)(bn * 128) * K;

  f32x4 acc[4][4];
#pragma unroll
  for (int i = 0; i < 4; ++i)
#pragma unroll
    for (int j = 0; j < 4; ++j)
#pragma unroll
      for (int r = 0; r < 4; ++r) acc[i][j][r] = 0.f;

  float4 areg[8];

  // A fp32 tile = 128 rows x 64 cols = 2048 x 16B granules; 8/thread.
  auto issueA = [&](int kt) {
    const int k0 = kt * 64;
#pragma unroll
    for (int j = 0; j < 8; ++j) {
      const int g = j * 256 + t;
      const int row = g >> 4;             // 16 granules (256B) per fp32 row
      const int cf = (g & 15) << 2;       // fp32 col 0..60 step 4
      areg[j] = *reinterpret_cast<const float4*>(gA + (size_t)row * K + k0 + cf);
    }
  };
  // split + write to swizzled LDS (same XOR the ds_read uses)
  auto writeA = [&]() {
#pragma unroll
    for (int j = 0; j < 8; ++j) {
      const int g = j * 256 + t;
      const int row = g >> 4;
      const int cb2 = (g & 15) << 3;      // fp16 byte col 0..120 step 8
      const float4 v = areg[j];
      ushort4 hv, lv;
      hv.x = f2h(v.x); lv.x = f2h(v.x - h2f(hv.x));
      hv.y = f2h(v.y); lv.y = f2h(v.y - h2f(hv.y));
      hv.z = f2h(v.z); lv.z = f2h(v.z - h2f(hv.z));
      hv.w = f2h(v.w); lv.w = f2h(v.w - h2f(hv.w));
      const int off = (row << 7) + (cb2 ^ ((row & 7) << 4));
      *reinterpret_cast<ushort4*>(reinterpret_cast<char*>(sAh) + off) = hv;
      *reinterpret_cast<ushort4*>(reinterpret_cast<char*>(sAl) + off) = lv;
    }
  };
  auto stageB = [&](int kt) {
    const int k0 = kt * 64;
#pragma unroll
    for (int i = 0; i < 4; ++i) {
      const int lin16 = i * 256 + t;
      const int lb = lin16 << 4;
      const int row = lb >> 7;
      const int srcb = (lb & 127) ^ ((row & 7) << 4);   // inverse swizzle on SOURCE
      const size_t goff = (size_t)row * K + (size_t)(k0 + (srcb >> 1));
      const int lidx = i * 2048 + w * 512;              // wave-uniform linear dest
      gload_lds16(gBh + goff, sBh + lidx);
      gload_lds16(gBl + goff, sBl + lidx);
    }
  };
  auto ldfrag = [&](const ushort* s, int row, int kc) -> half8 {
    const int byte = (row << 7) + ((kc << 1) ^ ((row & 7) << 4));
    return *reinterpret_cast<const half8*>(reinterpret_cast<const char*>(s) + byte);
  };

  const int NT = K / 64;
  stageB(0);
  issueA(0);
  writeA();            // compiler waits vmcnt for areg use, then ds_write
  __syncthreads();
  for (int kt = 0; kt < NT; ++kt) {
    if (kt + 1 < NT) issueA(kt + 1);   // early issue: hides under MFMA phase
#pragma unroll
    for (int kk = 0; kk < 2; ++kk) {
      half8 ah[4], al[4], bh[4], bl[4];
      const int kc = kk * 32 + lk;
#pragma unroll
      for (int i = 0; i < 4; ++i) {
        const int r = wm * 64 + i * 16 + lr;
        ah[i] = ldfrag(sAh, r, kc);
        al[i] = ldfrag(sAl, r, kc);
      }
#pragma unroll
      for (int j = 0; j < 4; ++j) {
        const int r = wn * 64 + j * 16 + lr;
        bh[j] = ldfrag(sBh, r, kc);
        bl[j] = ldfrag(sBl, r, kc);
      }
#pragma unroll
      for (int i = 0; i < 4; ++i)
#pragma unroll
        for (int j = 0; j < 4; ++j) {
          acc[i][j] = __builtin_amdgcn_mfma_f32_16x16x32_f16(ah[i], bh[j], acc[i][j], 0, 0, 0);
          acc[i][j] = __builtin_amdgcn_mfma_f32_16x16x32_f16(al[i], bh[j], acc[i][j], 0, 0, 0);
          acc[i][j] = __builtin_amdgcn_mfma_f32_16x16x32_f16(ah[i], bl[j], acc[i][j], 0, 0, 0);
        }
    }
    __syncthreads();                    // all LDS reads of tile kt done
    if (kt + 1 < NT) { stageB(kt + 1); writeA(); }
    __syncthreads();                    // staged tile kt+1 visible
  }

  // Epilogue: C/D layout col=lane&15, row=(lane>>4)*4+reg  [m89]
  float* Cb = C + (size_t)(bm * 128) * N + bn * 128;
#pragma unroll
  for (int i = 0; i < 4; ++i)
#pragma unroll
    for (int j = 0; j < 4; ++j) {
      const int col = wn * 64 + j * 16 + lr;
      const float bv = bias[bn * 128 + col];
#pragma unroll
      for (int r = 0; r < 4; ++r) {
        const int rowt = wm * 64 + i * 16 + ((lane >> 4) << 2) + r;
        Cb[(size_t)rowt * N + col] = (acc[i][j][r] + bv) * BX_SCALE;
      }
    }
}

// ---------------- GEMM2: y = h @ W_C^T + b_C, plain fp16 -------------------
__global__ __launch_bounds__(256, 2)
void k_gemm2(const ushort* __restrict__ Ah, const ushort* __restrict__ Bh,
             const float* __restrict__ bias, float* __restrict__ C,
             int M, int N, int K) {
  __shared__ __align__(1024) ushort lds[2 * 128 * 64];
  ushort* sAh = lds;
  ushort* sBh = lds + 8192;

  const int t = threadIdx.x;
  const int lane = t & 63;
  const int w = t >> 6;
  const int wm = w >> 1, wn = w & 1;

  int bm, bn;
  {
    const int l = blockIdx.y * 8 + blockIdx.x;
    const int xcd = l & 7, s = l >> 3;
    bm = ((s >> 3) << 3) | xcd;
    bn = s & 7;
  }

  const int lr = lane & 15;
  const int lk = (lane >> 4) << 3;

  const ushort* gA = Ah + (size_t)(bm * 128) * K;
  const ushort* gB = Bh + (size_t)(bn * 128) * K;

  f32x4 acc[4][4];
#pragma unroll
  for (int i = 0; i < 4; ++i)
#pragma unroll
    for (int j = 0; j < 4; ++j)
#pragma unroll
      for (int r = 0; r < 4; ++r) acc[i][j][r] = 0.f;

  auto stage = [&](int kt) {
    const int k0 = kt * 64;
#pragma unroll
    for (int i = 0; i < 4; ++i) {
      const int lin16 = i * 256 + t;
      const int lb = lin16 << 4;
      const int row = lb >> 7;
      const int srcb = (lb & 127) ^ ((row & 7) << 4);
      const size_t goff = (size_t)row * K + (size_t)(k0 + (srcb >> 1));
      const int lidx = i * 2048 + w * 512;
      gload_lds16(gA + goff, sAh + lidx);
      gload_lds16(gB + goff, sBh + lidx);
    }
  };
  auto ldfrag = [&](const ushort* s, int row, int kc) -> half8 {
    const int byte = (row << 7) + ((kc << 1) ^ ((row & 7) << 4));
    return *reinterpret_cast<const half8*>(reinterpret_cast<const char*>(s) + byte);
  };

  const int NT = K / 64;
  stage(0);
  for (int kt = 0; kt < NT; ++kt) {
    __syncthreads();
#pragma unroll
    for (int kk = 0; kk < 2; ++kk) {
      half8 ah[4], bh[4];
      const int kc = kk * 32 + lk;
#pragma unroll
      for (int i = 0; i < 4; ++i) ah[i] = ldfrag(sAh, wm * 64 + i * 16 + lr, kc);
#pragma unroll
      for (int j = 0; j < 4; ++j) bh[j] = ldfrag(sBh, wn * 64 + j * 16 + lr, kc);
#pragma unroll
      for (int i = 0; i < 4; ++i)
#pragma unroll
        for (int j = 0; j < 4; ++j)
          acc[i][j] = __builtin_amdgcn_mfma_f32_16x16x32_f16(ah[i], bh[j], acc[i][j], 0, 0, 0);
    }
    __syncthreads();
    if (kt + 1 < NT) stage(kt + 1);
  }

  float* Cb = C + (size_t)(bm * 128) * N + bn * 128;
#pragma unroll
  for (int i = 0; i < 4; ++i)
#pragma unroll
    for (int j = 0; j < 4; ++j) {
      const int col = wn * 64 + j * 16 + lr;
      const float bv = bias[bn * 128 + col];
#pragma unroll
      for (int r = 0; r < 4; ++r) {
        const int rowt = wm * 64 + i * 16 + ((lane >> 4) << 2) + r;
        Cb[(size_t)rowt * N + col] = acc[i][j][r] + bv;
      }
    }
}

// ---------------- sequential recurrence ----------------
// Bx2 = BX_SCALE*(x@W_B^T + b_B).  State r with h = 1-2r (r_init = 0.5).
// Critical chain per step (4 dep ops):
//   u2 = fma(-2a2, r, c_t)  ->  p = exp2(u2)  ->  q = p+1  ->  r = rcp(q)
// with c_t = a2 + bx_t precomputed at prefetch (off-chain), and the output
// h_t = fma(-2, r, 1) + cvt + store also off-chain.  No clamp needed:
// |u2| <= ~27, exp2 cannot overflow, rcp(p+1) is NaN-free.
// Ping-pong double buffer: each buffer reloads under the other's 32 steps.
__global__ __launch_bounds__(64)
void k_recurrence(const float* __restrict__ Bx2, const float* __restrict__ Avec,
                  ushort* __restrict__ Hout) {
  const int tid = blockIdx.x * 64 + threadIdx.x;   // 0..8191
  const int b = tid >> 10;
  const int d = tid & 1023;
  const float a2 = BX_SCALE * Avec[d];
  const float na2 = -2.f * a2;
  const float* bx = Bx2 + (size_t)b * 2048 * 1024 + d;
  ushort* ho = Hout + (size_t)b * 2048 * 1024 + d;

  constexpr int P = 32;
  constexpr int NC = 2048 / P;   // 64 chunks, even
  float cA[P], cB[P];
#pragma unroll
  for (int i = 0; i < P; ++i) cA[i] = a2 + bx[(size_t)i * 1024];
#pragma unroll
  for (int i = 0; i < P; ++i) cB[i] = a2 + bx[(size_t)(P + i) * 1024];

  float r = 0.5f;
  for (int c = 0; c < NC; c += 2) {
#pragma unroll
    for (int i = 0; i < P; ++i) {
      const float u2 = fmaf(na2, r, cA[i]);
      r = __builtin_amdgcn_rcpf(pexp(u2) + 1.f);
      ho[(size_t)(c * P + i) * 1024] = f2h(fmaf(-2.f, r, 1.f));
    }
    if (c + 2 < NC) {
#pragma unroll
      for (int i = 0; i < P; ++i) cA[i] = a2 + bx[(size_t)((c + 2) * P + i) * 1024];
    }
#pragma unroll
    for (int i = 0; i < P; ++i) {
      const float u2 = fmaf(na2, r, cB[i]);
      r = __builtin_amdgcn_rcpf(pexp(u2) + 1.f);
      ho[(size_t)((c + 1) * P + i) * 1024] = f2h(fmaf(-2.f, r, 1.f));
    }
    if (c + 3 < NC) {
#pragma unroll
      for (int i = 0; i < P; ++i) cB[i] = a2 + bx[(size_t)((c + 3) * P + i) * 1024];
    }
  }
}

// ---------------- launch ----------------
extern "C" void kernel_launch(void* const* d_in, const int* in_sizes, int n_in,
                              void* d_out, int out_size, void* d_ws, size_t ws_size,
                              hipStream_t stream) {
  const float* x   = (const float*)d_in[0];
  const float* A   = (const float*)d_in[1];
  const float* W_B = (const float*)d_in[2];
  const float* b_B = (const float*)d_in[3];
  const float* W_C = (const float*)d_in[4];
  const float* b_C = (const float*)d_in[5];
  float* y = (float*)d_out;

  const int Bsz = 8, L = 2048, D = 1024;
  const int M = Bsz * L;                       // 16384

  char* ws = (char*)d_ws;
  ushort* wbh = (ushort*)(ws);                  // 2MB fp16 W_B hi
  ushort* wbl = (ushort*)(ws + 2097152);        // 2MB fp16 W_B lo
  ushort* wch = (ushort*)(ws + 4194304);        // 2MB fp16 W_C
  float*  Bx  = (float*)(ws + 6291456);         // 64MB fp32 scaled Bx
  ushort* h   = (ushort*)(ws + 73400320);       // 32MB fp16 h

  k_convert_weights<<<512, 256, 0, stream>>>(W_B, W_C, wbh, wbl, wch, D * D / 4);

  k_gemm1_fused<<<dim3(8, M / 128), 256, 0, stream>>>(
      x, wbh, wbl, b_B, Bx, M, D, D);

  k_recurrence<<<(Bsz * D) / 64, 64, 0, stream>>>(Bx, A, h);

  k_gemm2<<<dim3(8, M / 128), 256, 0, stream>>>(
      h, wch, b_C, y, M, D, D);
}

// Round 6
// 238.318 us; speedup vs baseline: 1.0160x; 1.0160x over previous
//
#include <hip/hip_runtime.h>
#include <hip/hip_bf16.h>
#include <stdint.h>

// SimpleSSM: y = (scan_t h=tanh(A*h + x@W_B^T + b_B)) @ W_C^T + b_C
// B=8, L=2048, D=1024.  All fp32 in/out.
// R6: fused GEMM1 (x fp32 read directly, split to fp16 hi/lo on the fly)
// with the cvt HOISTED into the MFMA phase — only ds_writes remain in the
// serialized between-barrier section (R5's regression was the cvt chain
// there). Split is mandatory (R2/R3: plain bf16/fp16 chaos-amplify to 0.25
// absmax; splits pass at 0.0156). Recurrence: 4-dep-op chain on r-state.

using half8 = __attribute__((ext_vector_type(8))) _Float16;  // 8 fp16
using f32x4 = __attribute__((ext_vector_type(4))) float;

#define DEV __device__ __forceinline__

#if __has_builtin(__builtin_amdgcn_exp2f)
DEV float pexp(float x) { return __builtin_amdgcn_exp2f(x); }
constexpr float BX_SCALE = 2.8853900817779268f;   // 2*log2(e): exp2 domain
#else
DEV float pexp(float x) { return __expf(x); }
constexpr float BX_SCALE = 2.0f;                   // e^x domain
#endif

DEV ushort f2h(float x) {
  union { _Float16 f; ushort u; } c;
  c.f = (_Float16)x;          // v_cvt_f16_f32, RNE
  return c.u;
}
DEV float h2f(ushort u) {
  union { ushort u; _Float16 f; } c;
  c.u = u;
  return (float)c.f;
}

DEV void gload_lds16(const void* g, void* l) {
  __builtin_amdgcn_global_load_lds((const __attribute__((address_space(1))) void*)g,
                                   (__attribute__((address_space(3))) void*)l,
                                   16, 0, 0);
}

// ---------------- fused weights conversion ----------------
// W_B -> fp16 hi+lo split; W_C -> fp16.  One launch.
__global__ void k_convert_weights(const float* __restrict__ WB, const float* __restrict__ WC,
                                  ushort* __restrict__ wbh, ushort* __restrict__ wbl,
                                  ushort* __restrict__ wch, int n4) {
  const int stride = gridDim.x * blockDim.x;
  for (int i = blockIdx.x * blockDim.x + threadIdx.x; i < 2 * n4; i += stride) {
    if (i < n4) {
      float4 v = reinterpret_cast<const float4*>(WB)[i];
      ushort4 hv, lv;
      hv.x = f2h(v.x); lv.x = f2h(v.x - h2f(hv.x));
      hv.y = f2h(v.y); lv.y = f2h(v.y - h2f(hv.y));
      hv.z = f2h(v.z); lv.z = f2h(v.z - h2f(hv.z));
      hv.w = f2h(v.w); lv.w = f2h(v.w - h2f(hv.w));
      reinterpret_cast<ushort4*>(wbh)[i] = hv;
      reinterpret_cast<ushort4*>(wbl)[i] = lv;
    } else {
      const int j = i - n4;
      float4 v = reinterpret_cast<const float4*>(WC)[j];
      ushort4 hv;
      hv.x = f2h(v.x); hv.y = f2h(v.y);
      hv.z = f2h(v.z); hv.w = f2h(v.w);
      reinterpret_cast<ushort4*>(wch)[j] = hv;
    }
  }
}

// ---------------- GEMM1: Bx = BX_SCALE*(x @ W_B^T + b_B), split-fp16 -------
// A = x fp32 [M,K], split to (hi,lo) in regs; B = weights hi/lo fp16.
// 128x128 tile, BK=64, 4 waves (2x2). acc += Ah*Bh + Al*Bh + Ah*Bl.
// Per K-iter: issueA(kt+1) at phase start (latency under 96 MFMAs);
// cvtA at phase end (VALU co-issues with MFMA pipe); between barriers only
// ds_writes + global_load_lds issue.  B: pre-swizzled source (rule #21).
__global__ __launch_bounds__(256, 2)
void k_gemm1_fused(const float* __restrict__ X, const ushort* __restrict__ Bh,
                   const ushort* __restrict__ Bl, const float* __restrict__ bias,
                   float* __restrict__ C, int M, int N, int K) {
  __shared__ __align__(1024) ushort lds[4 * 128 * 64];
  ushort* sAh = lds;
  ushort* sAl = lds + 8192;
  ushort* sBh = lds + 16384;
  ushort* sBl = lds + 24576;

  const int t = threadIdx.x;
  const int lane = t & 63;
  const int w = t >> 6;
  const int wm = w >> 1, wn = w & 1;

  // XCD-bijective remap (grid 8 x 128): l=8*by+bx, xcd=l&7, s=l>>3;
  // bm=(s&~7)|xcd, bn=s&7.
  int bm, bn;
  {
    const int l = blockIdx.y * 8 + blockIdx.x;
    const int xcd = l & 7, s = l >> 3;
    bm = ((s >> 3) << 3) | xcd;
    bn = s & 7;
  }

  const int lr = lane & 15;
  const int lk = (lane >> 4) << 3;

  const float*  gA  = X  + (size_t)(bm * 128) * K;
  const ushort* gBh = Bh + (size_t)(bn * 128) * K;
  const ushort* gBl = Bl + (size_t)(bn * 128) * K;

  f32x4 acc[4][4];
#pragma unroll
  for (int i = 0; i < 4; ++i)
#pragma unroll
    for (int j = 0; j < 4; ++j)
#pragma unroll
      for (int r = 0; r < 4; ++r) acc[i][j][r] = 0.f;

  float4  areg[8];
  ushort4 hreg[8], lreg[8];

  // A fp32 tile = 128 rows x 64 cols = 2048 x 16B granules; 8/thread.
  auto issueA = [&](int kt) {
    const int k0 = kt * 64;
#pragma unroll
    for (int j = 0; j < 8; ++j) {
      const int g = j * 256 + t;
      const int row = g >> 4;             // 16 granules (256B) per fp32 row
      const int cf = (g & 15) << 2;       // fp32 col 0..60 step 4
      areg[j] = *reinterpret_cast<const float4*>(gA + (size_t)row * K + k0 + cf);
    }
  };
  // split conversion in regs (runs inside the MFMA phase)
  auto cvtA = [&]() {
#pragma unroll
    for (int j = 0; j < 8; ++j) {
      const float4 v = areg[j];
      ushort4 hv, lv;
      hv.x = f2h(v.x); lv.x = f2h(v.x - h2f(hv.x));
      hv.y = f2h(v.y); lv.y = f2h(v.y - h2f(hv.y));
      hv.z = f2h(v.z); lv.z = f2h(v.z - h2f(hv.z));
      hv.w = f2h(v.w); lv.w = f2h(v.w - h2f(hv.w));
      hreg[j] = hv; lreg[j] = lv;
    }
  };
  // pure ds_writes to swizzled offsets (the only A-work between barriers)
  auto writeA = [&]() {
#pragma unroll
    for (int j = 0; j < 8; ++j) {
      const int g = j * 256 + t;
      const int row = g >> 4;
      const int cb2 = (g & 15) << 3;      // fp16 byte col 0..120 step 8
      const int off = (row << 7) + (cb2 ^ ((row & 7) << 4));
      *reinterpret_cast<ushort4*>(reinterpret_cast<char*>(sAh) + off) = hreg[j];
      *reinterpret_cast<ushort4*>(reinterpret_cast<char*>(sAl) + off) = lreg[j];
    }
  };
  auto stageB = [&](int kt) {
    const int k0 = kt * 64;
#pragma unroll
    for (int i = 0; i < 4; ++i) {
      const int lin16 = i * 256 + t;
      const int lb = lin16 << 4;
      const int row = lb >> 7;
      const int srcb = (lb & 127) ^ ((row & 7) << 4);   // inverse swizzle on SOURCE
      const size_t goff = (size_t)row * K + (size_t)(k0 + (srcb >> 1));
      const int lidx = i * 2048 + w * 512;              // wave-uniform linear dest
      gload_lds16(gBh + goff, sBh + lidx);
      gload_lds16(gBl + goff, sBl + lidx);
    }
  };
  auto ldfrag = [&](const ushort* s, int row, int kc) -> half8 {
    const int byte = (row << 7) + ((kc << 1) ^ ((row & 7) << 4));
    return *reinterpret_cast<const half8*>(reinterpret_cast<const char*>(s) + byte);
  };

  const int NT = K / 64;
  // prologue: tile 0
  issueA(0); cvtA(); writeA();
  stageB(0);
  __syncthreads();
  for (int kt = 0; kt < NT; ++kt) {
    if (kt + 1 < NT) issueA(kt + 1);   // HBM latency hides under MFMAs
#pragma unroll
    for (int kk = 0; kk < 2; ++kk) {
      half8 ah[4], al[4], bh[4], bl[4];
      const int kc = kk * 32 + lk;
#pragma unroll
      for (int i = 0; i < 4; ++i) {
        const int r = wm * 64 + i * 16 + lr;
        ah[i] = ldfrag(sAh, r, kc);
        al[i] = ldfrag(sAl, r, kc);
      }
#pragma unroll
      for (int j = 0; j < 4; ++j) {
        const int r = wn * 64 + j * 16 + lr;
        bh[j] = ldfrag(sBh, r, kc);
        bl[j] = ldfrag(sBl, r, kc);
      }
#pragma unroll
      for (int i = 0; i < 4; ++i)
#pragma unroll
        for (int j = 0; j < 4; ++j) {
          acc[i][j] = __builtin_amdgcn_mfma_f32_16x16x32_f16(ah[i], bh[j], acc[i][j], 0, 0, 0);
          acc[i][j] = __builtin_amdgcn_mfma_f32_16x16x32_f16(al[i], bh[j], acc[i][j], 0, 0, 0);
          acc[i][j] = __builtin_amdgcn_mfma_f32_16x16x32_f16(ah[i], bl[j], acc[i][j], 0, 0, 0);
        }
    }
    if (kt + 1 < NT) cvtA();            // VALU, co-issues with MFMA drain
    __syncthreads();                    // all LDS reads of tile kt done
    if (kt + 1 < NT) { writeA(); stageB(kt + 1); }
    __syncthreads();                    // staged tile kt+1 visible
  }

  // Epilogue: C/D layout col=lane&15, row=(lane>>4)*4+reg  [m89]
  float* Cb = C + (size_t)(bm * 128) * N + bn * 128;
#pragma unroll
  for (int i = 0; i < 4; ++i)
#pragma unroll
    for (int j = 0; j < 4; ++j) {
      const int col = wn * 64 + j * 16 + lr;
      const float bv = bias[bn * 128 + col];
#pragma unroll
      for (int r = 0; r < 4; ++r) {
        const int rowt = wm * 64 + i * 16 + ((lane >> 4) << 2) + r;
        Cb[(size_t)rowt * N + col] = (acc[i][j][r] + bv) * BX_SCALE;
      }
    }
}

// ---------------- GEMM2: y = h @ W_C^T + b_C, plain fp16 -------------------
__global__ __launch_bounds__(256, 2)
void k_gemm2(const ushort* __restrict__ Ah, const ushort* __restrict__ Bh,
             const float* __restrict__ bias, float* __restrict__ C,
             int M, int N, int K) {
  __shared__ __align__(1024) ushort lds[2 * 128 * 64];
  ushort* sAh = lds;
  ushort* sBh = lds + 8192;

  const int t = threadIdx.x;
  const int lane = t & 63;
  const int w = t >> 6;
  const int wm = w >> 1, wn = w & 1;

  int bm, bn;
  {
    const int l = blockIdx.y * 8 + blockIdx.x;
    const int xcd = l & 7, s = l >> 3;
    bm = ((s >> 3) << 3) | xcd;
    bn = s & 7;
  }

  const int lr = lane & 15;
  const int lk = (lane >> 4) << 3;

  const ushort* gA = Ah + (size_t)(bm * 128) * K;
  const ushort* gB = Bh + (size_t)(bn * 128) * K;

  f32x4 acc[4][4];
#pragma unroll
  for (int i = 0; i < 4; ++i)
#pragma unroll
    for (int j = 0; j < 4; ++j)
#pragma unroll
      for (int r = 0; r < 4; ++r) acc[i][j][r] = 0.f;

  auto stage = [&](int kt) {
    const int k0 = kt * 64;
#pragma unroll
    for (int i = 0; i < 4; ++i) {
      const int lin16 = i * 256 + t;
      const int lb = lin16 << 4;
      const int row = lb >> 7;
      const int srcb = (lb & 127) ^ ((row & 7) << 4);
      const size_t goff = (size_t)row * K + (size_t)(k0 + (srcb >> 1));
      const int lidx = i * 2048 + w * 512;
      gload_lds16(gA + goff, sAh + lidx);
      gload_lds16(gB + goff, sBh + lidx);
    }
  };
  auto ldfrag = [&](const ushort* s, int row, int kc) -> half8 {
    const int byte = (row << 7) + ((kc << 1) ^ ((row & 7) << 4));
    return *reinterpret_cast<const half8*>(reinterpret_cast<const char*>(s) + byte);
  };

  const int NT = K / 64;
  stage(0);
  for (int kt = 0; kt < NT; ++kt) {
    __syncthreads();
#pragma unroll
    for (int kk = 0; kk < 2; ++kk) {
      half8 ah[4], bh[4];
      const int kc = kk * 32 + lk;
#pragma unroll
      for (int i = 0; i < 4; ++i) ah[i] = ldfrag(sAh, wm * 64 + i * 16 + lr, kc);
#pragma unroll
      for (int j = 0; j < 4; ++j) bh[j] = ldfrag(sBh, wn * 64 + j * 16 + lr, kc);
#pragma unroll
      for (int i = 0; i < 4; ++i)
#pragma unroll
        for (int j = 0; j < 4; ++j)
          acc[i][j] = __builtin_amdgcn_mfma_f32_16x16x32_f16(ah[i], bh[j], acc[i][j], 0, 0, 0);
    }
    __syncthreads();
    if (kt + 1 < NT) stage(kt + 1);
  }

  float* Cb = C + (size_t)(bm * 128) * N + bn * 128;
#pragma unroll
  for (int i = 0; i < 4; ++i)
#pragma unroll
    for (int j = 0; j < 4; ++j) {
      const int col = wn * 64 + j * 16 + lr;
      const float bv = bias[bn * 128 + col];
#pragma unroll
      for (int r = 0; r < 4; ++r) {
        const int rowt = wm * 64 + i * 16 + ((lane >> 4) << 2) + r;
        Cb[(size_t)rowt * N + col] = acc[i][j][r] + bv;
      }
    }
}

// ---------------- sequential recurrence ----------------
// Bx2 = BX_SCALE*(x@W_B^T + b_B).  State r with h = 1-2r (r_init = 0.5).
// Critical chain per step (4 dep ops):
//   u2 = fma(-2a2, r, c_t)  ->  p = exp2(u2)  ->  q = p+1  ->  r = rcp(q)
// c_t = a2 + bx_t precomputed off-chain; output h_t = fma(-2,r,1)+cvt+store
// also off-chain.  No clamp: |u2| <= ~27, exp2 cannot overflow.
// Ping-pong double buffer: each buffer reloads under the other's 32 steps.
__global__ __launch_bounds__(64)
void k_recurrence(const float* __restrict__ Bx2, const float* __restrict__ Avec,
                  ushort* __restrict__ Hout) {
  const int tid = blockIdx.x * 64 + threadIdx.x;   // 0..8191
  const int b = tid >> 10;
  const int d = tid & 1023;
  const float a2 = BX_SCALE * Avec[d];
  const float na2 = -2.f * a2;
  const float* bx = Bx2 + (size_t)b * 2048 * 1024 + d;
  ushort* ho = Hout + (size_t)b * 2048 * 1024 + d;

  constexpr int P = 32;
  constexpr int NC = 2048 / P;   // 64 chunks, even
  float cA[P], cB[P];
#pragma unroll
  for (int i = 0; i < P; ++i) cA[i] = a2 + bx[(size_t)i * 1024];
#pragma unroll
  for (int i = 0; i < P; ++i) cB[i] = a2 + bx[(size_t)(P + i) * 1024];

  float r = 0.5f;
  for (int c = 0; c < NC; c += 2) {
#pragma unroll
    for (int i = 0; i < P; ++i) {
      const float u2 = fmaf(na2, r, cA[i]);
      r = __builtin_amdgcn_rcpf(pexp(u2) + 1.f);
      ho[(size_t)(c * P + i) * 1024] = f2h(fmaf(-2.f, r, 1.f));
    }
    if (c + 2 < NC) {
#pragma unroll
      for (int i = 0; i < P; ++i) cA[i] = a2 + bx[(size_t)((c + 2) * P + i) * 1024];
    }
#pragma unroll
    for (int i = 0; i < P; ++i) {
      const float u2 = fmaf(na2, r, cB[i]);
      r = __builtin_amdgcn_rcpf(pexp(u2) + 1.f);
      ho[(size_t)((c + 1) * P + i) * 1024] = f2h(fmaf(-2.f, r, 1.f));
    }
    if (c + 3 < NC) {
#pragma unroll
      for (int i = 0; i < P; ++i) cB[i] = a2 + bx[(size_t)((c + 3) * P + i) * 1024];
    }
  }
}

// ---------------- launch ----------------
extern "C" void kernel_launch(void* const* d_in, const int* in_sizes, int n_in,
                              void* d_out, int out_size, void* d_ws, size_t ws_size,
                              hipStream_t stream) {
  const float* x   = (const float*)d_in[0];
  const float* A   = (const float*)d_in[1];
  const float* W_B = (const float*)d_in[2];
  const float* b_B = (const float*)d_in[3];
  const float* W_C = (const float*)d_in[4];
  const float* b_C = (const float*)d_in[5];
  float* y = (float*)d_out;

  const int Bsz = 8, L = 2048, D = 1024;
  const int M = Bsz * L;                       // 16384

  char* ws = (char*)d_ws;
  ushort* wbh = (ushort*)(ws);                  // 2MB fp16 W_B hi
  ushort* wbl = (ushort*)(ws + 2097152);        // 2MB fp16 W_B lo
  ushort* wch = (ushort*)(ws + 4194304);        // 2MB fp16 W_C
  float*  Bx  = (float*)(ws + 6291456);         // 64MB fp32 scaled Bx
  ushort* h   = (ushort*)(ws + 73400320);       // 32MB fp16 h

  k_convert_weights<<<512, 256, 0, stream>>>(W_B, W_C, wbh, wbl, wch, D * D / 4);

  k_gemm1_fused<<<dim3(8, M / 128), 256, 0, stream>>>(
      x, wbh, wbl, b_B, Bx, M, D, D);

  k_recurrence<<<(Bsz * D) / 64, 64, 0, stream>>>(Bx, A, h);

  k_gemm2<<<dim3(8, M / 128), 256, 0, stream>>>(
      h, wch, b_C, y, M, D, D);
}